// Round 5
// baseline (1691.137 us; speedup 1.0000x reference)
//
#include <hip/hip_runtime.h>

// ---------------------------------------------------------------------------
// XiRNN (peephole LSTM) on MI355X.  B=64, T=188, I=512, H=R=1024.
//   k_prep : fp32->bf16 conversion; W_rec split into bf16 hi+lo; zero flags.
//   k_px   : px[t][gate][j][b] = x[b,t,:]·W_ih[gate*H+j,:] + bias (MFMA GEMM)
//   k_scan : persistent kernel, 256 blocks (1/CU), 4 batch-groups of 16 rows
//            x 64 CUs. Weights register-resident. Peephole in compensated
//            bf16. c fp32 in LDS locally; cross-CU state bf16 (c hi/lo).
//   R9 (1156us): batched 16B sc0 sc1 state gather -> one L3 RT.
//   R10 FAILED (2050us): all-wave busy-poll flooded the coherent fabric.
//   R11 (1140us): go_word release + weak ballast. DVFS test inconclusive
//   (ballast duty ~10%: waves still stalled on poll-load RTs; VALUBusy 17%).
//   R12: balance + producer-tail trim, same protocol family:
//     - Balanced 4-wave split: each wave owns K=256, computes ALL 10 products
//       (4 gates + 6 peephole partials) = 80 MFMAs + 24 gather loads. Before:
//       ts0 64 MFMA/16 loads vs ts1 96/32 -> both barriers joined on ts1.
//     - Per-wave flags (flags[cu*4+wv]) posted after each wave's OWN vmcnt(0)
//       drain; post-epilogue barrier deleted. Consumer wave0 lane i polls
//       producer i's 4 wave-flags with one dwordx4 + min-reduce (probe
//       transaction count unchanged vs R9 -> no R10-style fabric flood).
//     - Denser ballast (4 indep FMA chains x 16) as a real DVFS probe.
//   Skew safety: release(t+1) includes own CU's 4 wave-flags => all own waves
//   past epilogue(t); pre[]/state parity double-buffers cover the rest
//   (same invariant as R9/R11).
// ---------------------------------------------------------------------------

#define T_N 188

// ws byte offsets (256-aligned). Total = 132,648,960 B (~126.5 MiB).
#define WS_PX     0UL           // ushort[188*4096*64]   = 98,566,144 B
#define WS_XB     98566144UL    // ushort[64*188*512]    = 12,320,768 B
#define WS_WIHB   110886912UL   // ushort[4096*512]      =  4,194,304 B
#define WS_WCOMB  115081216UL   // ushort[6144*1024]     = 12,582,912 B
#define WS_HST    127664128UL   // ushort[2][64][1024]   =    262,144 B
#define WS_CST    127926272UL   // ushort[2][64][1024]   =    262,144 B
#define WS_FLAGS  128188416UL   // int[1024] = [256 cu][4 wave]
#define WS_WRECLO 128192512UL   // ushort[2048*1024]     =  4,194,304 B
#define WS_CSTLO  132386816UL   // ushort[2][64][1024]   =    262,144 B

typedef __attribute__((ext_vector_type(8))) short short8;
typedef __attribute__((ext_vector_type(4))) float f4;
typedef __attribute__((ext_vector_type(4))) int int4v;

__device__ __forceinline__ float b2f(unsigned short u) {
    union { unsigned int i; float f; } v; v.i = ((unsigned int)u) << 16; return v.f;
}
__device__ __forceinline__ unsigned short f2b(float f) {
    unsigned int u = __float_as_uint(f);
    return (unsigned short)((u + 0x7FFFu + ((u >> 16) & 1u)) >> 16);
}
__device__ __forceinline__ float sigf(float x) { return 1.0f / (1.0f + __expf(-x)); }
__device__ __forceinline__ float tanh_(float x) {
    float e = __expf(2.0f * x); return 1.0f - 2.0f / (e + 1.0f);
}
#define MFMA(a, b, c) __builtin_amdgcn_mfma_f32_16x16x32_bf16((a), (b), (c), 0, 0, 0)

// 16B device-coherent load (bypass L1/L2). Result NOT tracked by compiler
// waitcnt logic — caller must s_waitcnt vmcnt(0) + sched_barrier(0) before use.
#define LD16(dst, addr) \
    asm volatile("global_load_dwordx4 %0, %1, off sc0 sc1" : "=&v"(dst) : "v"(addr))

// 64-FMA ballast burst, 4 independent chains: ~64 issue cycles of real VALU
// activity per wait iteration (R11's single 16-FMA chain gave only ~10% duty).
#define BAL64()                                                            \
    _Pragma("unroll")                                                      \
    for (int u_ = 0; u_ < 16; ++u_) {                                      \
        bl0 = __builtin_fmaf(bl0, 1.0000001f, 1e-7f);                      \
        bl1 = __builtin_fmaf(bl1, 1.0000001f, 2e-7f);                      \
        bl2 = __builtin_fmaf(bl2, 1.0000001f, 3e-7f);                      \
        bl3 = __builtin_fmaf(bl3, 1.0000001f, 4e-7f);                      \
    }

__device__ __forceinline__ f4 px_init(const unsigned short* px, int t, int gate, int jg, int brow) {
    unsigned long long pv =
        *(const unsigned long long*)(px + ((long)(t * 4 + gate) * 1024 + jg) * 64 + brow);
    f4 r;
    r[0] = b2f((unsigned short)pv);
    r[1] = b2f((unsigned short)(pv >> 16));
    r[2] = b2f((unsigned short)(pv >> 32));
    r[3] = b2f((unsigned short)(pv >> 48));
    return r;
}

// ---------------------------------------------------------------------------
__global__ void k_prep(const float* __restrict__ x, const float* __restrict__ h0,
                       const float* __restrict__ c0, const float* __restrict__ wih,
                       const float* __restrict__ whh, const float* __restrict__ wrec,
                       unsigned short* __restrict__ xb, unsigned short* __restrict__ wihb,
                       unsigned short* __restrict__ wcomb, unsigned short* __restrict__ hst,
                       unsigned short* __restrict__ cst, unsigned short* __restrict__ wreclo,
                       unsigned short* __restrict__ cstlo, int* __restrict__ flags) {
    const long NX4 = 1540096, NWIH4 = 524288, NWHH4 = 1048576, NWREC4 = 524288, NH4 = 16384;
    const long total = NX4 + NWIH4 + NWHH4 + NWREC4 + NH4 + NH4;
    long gtid = (long)blockIdx.x * blockDim.x + threadIdx.x;
    for (long i = gtid; i < total; i += (long)gridDim.x * blockDim.x) {
        const float* src; unsigned short* dst; unsigned short* lo_dst = nullptr; long off = i;
        if (off < NX4)                   { src = x;    dst = xb; }
        else if ((off -= NX4) < NWIH4)   { src = wih;  dst = wihb; }
        else if ((off -= NWIH4) < NWHH4) { src = whh;  dst = wcomb; }
        else if ((off -= NWHH4) < NWREC4){ src = wrec; dst = wcomb + 4194304; lo_dst = wreclo; }
        else if ((off -= NWREC4) < NH4)  { src = h0;   dst = hst + 65536; }     // state slot 1
        else { off -= NH4;                 src = c0;   dst = cst + 65536; lo_dst = cstlo + 65536; }
        float4 v = ((const float4*)src)[off];
        unsigned short hx = f2b(v.x), hy = f2b(v.y), hz = f2b(v.z), hw = f2b(v.w);
        unsigned long long o = (unsigned long long)hx
            | ((unsigned long long)hy << 16)
            | ((unsigned long long)hz << 32)
            | ((unsigned long long)hw << 48);
        *(unsigned long long*)(dst + off * 4) = o;
        if (lo_dst) {
            unsigned long long l = (unsigned long long)f2b(v.x - b2f(hx))
                | ((unsigned long long)f2b(v.y - b2f(hy)) << 16)
                | ((unsigned long long)f2b(v.z - b2f(hz)) << 32)
                | ((unsigned long long)f2b(v.w - b2f(hw)) << 48);
            *(unsigned long long*)(lo_dst + off * 4) = l;
        }
    }
    if (gtid < 1024) flags[gtid] = 0;
}

// ---------------------------------------------------------------------------
// px GEMM: block = (t, 64-col slab), 4 waves, each wave one 16-col tile, M=64.
__global__ void __launch_bounds__(256) k_px(const unsigned short* __restrict__ xb,
                                            const unsigned short* __restrict__ wihb,
                                            const float* __restrict__ bias,
                                            unsigned short* __restrict__ px) {
    const int t = blockIdx.y;
    const int wv = threadIdx.x >> 6, lane = threadIdx.x & 63;
    const int col = lane & 15, quad = lane >> 4;
    const int n = blockIdx.x * 64 + wv * 16 + col;   // 0..4095 combined gate*H+j
    const float bn = bias[n];
    f4 acc[4];
#pragma unroll
    for (int mt = 0; mt < 4; ++mt) { acc[mt][0] = bn; acc[mt][1] = bn; acc[mt][2] = bn; acc[mt][3] = bn; }
    const unsigned short* bp = wihb + n * 512 + quad * 8;
#pragma unroll 4
    for (int kk = 0; kk < 16; ++kk) {
        short8 bf = *(const short8*)(bp + kk * 32);
#pragma unroll
        for (int mt = 0; mt < 4; ++mt) {
            const unsigned short* ap = xb + ((mt * 16 + col) * 188 + t) * 512 + kk * 32 + quad * 8;
            short8 af = *(const short8*)ap;
            acc[mt] = MFMA(af, bf, acc[mt]);
        }
    }
    const long pb = ((long)(t * 4 + (n >> 10)) * 1024 + (n & 1023)) * 64;
#pragma unroll
    for (int mt = 0; mt < 4; ++mt) {
        unsigned long long o = (unsigned long long)f2b(acc[mt][0])
            | ((unsigned long long)f2b(acc[mt][1]) << 16)
            | ((unsigned long long)f2b(acc[mt][2]) << 32)
            | ((unsigned long long)f2b(acc[mt][3]) << 48);
        *(unsigned long long*)(px + pb + mt * 16 + quad * 4) = o;
    }
}

// ---------------------------------------------------------------------------
// Persistent scan. cu = blockIdx: group g = cu>>6 (16 batch rows), cig = cu&63
// (16 hidden indices). R12: 4 balanced waves, each owns K-slice kbase=wv*256
// and computes ALL products over its slice:
//   gates i,f,g,o  : h @ W_hh         (4 acc chains)
//   peephole ri,rf : c_hi@W_hi + c_hi@W_lo + c_lo@W_hi  (6 acc chains)
// 80 MFMAs + 24 state loads per wave. Wave 0 additionally seeds px and runs
// the flag poll; waves 1-3 spin on the LDS go_word (R11).
__global__ void __launch_bounds__(256, 1) k_scan(
    const unsigned short* __restrict__ wcomb, const unsigned short* __restrict__ wreclo,
    const float* __restrict__ c0, const int* __restrict__ lengths,
    const unsigned short* __restrict__ px, unsigned short* __restrict__ hst,
    unsigned short* __restrict__ cst, unsigned short* __restrict__ cstlo,
    int* __restrict__ flags, float* __restrict__ out) {
    const int cu = blockIdx.x;
    const int g = cu >> 6, cig = cu & 63;
    const int jbase = cig * 16, b0 = g * 16;
    const int tid = threadIdx.x, wv = tid >> 6, lane = tid & 63;
    const int kbase = wv * 256;               // per-wave K-slice
    const int col = lane & 15, quad = lane >> 4;
    const int b_ = tid >> 4, j_ = tid & 15;

    __shared__ float pre[2][4][6][16][16];   // [slot][kq][tile][b][j]  48 KB
    __shared__ float c_loc[16][16];          // fp32 local c (never rounded)
    __shared__ int go_word;                  // LDS release hand-off

    // One-time: weights -> regs. Per wave: 8 tiles x 8 k-chunks x 16B/lane.
    short8 wg[4][8];   // i,f,g,o rows of W_hh            (rows 0..4095)
    short8 wh[2][8];   // ri_hi, rf_hi rows of W_rec hi   (rows 4096..6143)
    short8 wl[2][8];   // ri_lo, rf_lo rows of W_rec lo
#pragma unroll
    for (int gate = 0; gate < 4; ++gate) {
        const unsigned short* src = wcomb + (long)(gate * 1024 + jbase + col) * 1024 + kbase + quad * 8;
#pragma unroll
        for (int kk = 0; kk < 8; ++kk) wg[gate][kk] = *(const short8*)(src + kk * 32);
    }
#pragma unroll
    for (int tl = 0; tl < 2; ++tl) {
        const unsigned short* sh = wcomb + (long)((4 + tl) * 1024 + jbase + col) * 1024 + kbase + quad * 8;
        const unsigned short* sl = wreclo + (long)(tl * 1024 + jbase + col) * 1024 + kbase + quad * 8;
#pragma unroll
        for (int kk = 0; kk < 8; ++kk) {
            wh[tl][kk] = *(const short8*)(sh + kk * 32);
            wl[tl][kk] = *(const short8*)(sl + kk * 32);
        }
    }
    c_loc[b_][j_] = c0[(b0 + b_) * 1024 + jbase + j_];
    if (tid == 0) go_word = 0;
    const int my_len = lengths[b0 + b_];
    float bl0 = (float)lane + 1.0f, bl1 = bl0 + 0.5f, bl2 = bl0 + 0.25f, bl3 = bl0 + 0.125f;
    __syncthreads();

    float* out_h = out;
    float* out_c = out + 12320768;

    for (int t = 0; t < T_N; ++t) {
        const int sl_r = (t + 1) & 1, sl_w = t & 1, ps = t & 1;

        // px loads (wave 0 only — gates 0..3) are state-independent: issue
        // before the poll so they're in flight while we wait.
        f4 pxv[4];
        if (wv == 0) {
#pragma unroll
            for (int tile = 0; tile < 4; ++tile)
                pxv[tile] = px_init(px, t, tile, jbase + col, b0 + quad * 4);
        }

        if (t > 0) {
            if (wv == 0) {
                // Lane i watches producer CU i's 4 wave-flags (one dwordx4),
                // min-reduces, releases the block via go_word when all >= t.
                const int* fp = flags + (g * 64 + lane) * 4;
                for (;;) {
                    int4v fvv;
                    asm volatile("global_load_dwordx4 %0, %1, off sc0 sc1" : "=&v"(fvv) : "v"(fp));
                    asm volatile("s_waitcnt vmcnt(0)" ::: "memory");
                    int m0 = fvv[0] < fvv[1] ? fvv[0] : fvv[1];
                    int m1 = fvv[2] < fvv[3] ? fvv[2] : fvv[3];
                    int m = m0 < m1 ? m0 : m1;
                    if (__all(m >= t)) break;
                    BAL64();
                }
                if (lane == 0)
                    __hip_atomic_store(&go_word, t, __ATOMIC_RELAXED, __HIP_MEMORY_SCOPE_WORKGROUP);
            } else {
                for (;;) {
                    int gw = __hip_atomic_load(&go_word, __ATOMIC_RELAXED, __HIP_MEMORY_SCOPE_WORKGROUP);
                    if (gw >= t) break;
                    BAL64();
                }
            }
            asm volatile("" ::: "memory");
        }

        const int sbase = sl_r * 65536 + (b0 + col) * 1024 + kbase + quad * 8;

        // Batched gather: this wave's K-slice of h, c_hi, c_lo (24 x 16B).
        short8 hb[8], cb[8], lb[8];
#pragma unroll
        for (int kk = 0; kk < 8; ++kk) LD16(hb[kk], hst + sbase + kk * 32);
#pragma unroll
        for (int kk = 0; kk < 8; ++kk) LD16(cb[kk], cst + sbase + kk * 32);
#pragma unroll
        for (int kk = 0; kk < 8; ++kk) LD16(lb[kk], cstlo + sbase + kk * 32);

        f4 ag0, ag1, ag2, ag3;
        if (wv == 0) { ag0 = pxv[0]; ag1 = pxv[1]; ag2 = pxv[2]; ag3 = pxv[3]; }
        else {
            ag0[0] = 0.f; ag0[1] = 0.f; ag0[2] = 0.f; ag0[3] = 0.f;
            ag1 = ag0; ag2 = ag0; ag3 = ag0;
        }
        f4 ap0 = {0.f, 0.f, 0.f, 0.f}, ap1 = ap0, ap2 = ap0, ap3 = ap0, ap4 = ap0, ap5 = ap0;

        asm volatile("s_waitcnt vmcnt(0)" ::: "memory");
        __builtin_amdgcn_sched_barrier(0);
#pragma unroll
        for (int kk = 0; kk < 8; ++kk) {
            ag0 = MFMA(hb[kk], wg[0][kk], ag0);
            ag1 = MFMA(hb[kk], wg[1][kk], ag1);
            ag2 = MFMA(hb[kk], wg[2][kk], ag2);
            ag3 = MFMA(hb[kk], wg[3][kk], ag3);
            ap0 = MFMA(cb[kk], wh[0][kk], ap0);   // c_hi @ ri_hi
            ap1 = MFMA(cb[kk], wh[1][kk], ap1);   // c_hi @ rf_hi
            ap2 = MFMA(cb[kk], wl[0][kk], ap2);   // c_hi @ ri_lo
            ap3 = MFMA(cb[kk], wl[1][kk], ap3);   // c_hi @ rf_lo
            ap4 = MFMA(lb[kk], wh[0][kk], ap4);   // c_lo @ ri_hi
            ap5 = MFMA(lb[kk], wh[1][kk], ap5);   // c_lo @ rf_hi
        }
#pragma unroll
        for (int r = 0; r < 4; ++r) {
            pre[ps][wv][0][quad * 4 + r][col] = ag0[r];
            pre[ps][wv][1][quad * 4 + r][col] = ag1[r];
            pre[ps][wv][2][quad * 4 + r][col] = ag2[r];
            pre[ps][wv][3][quad * 4 + r][col] = ag3[r];
            pre[ps][wv][4][quad * 4 + r][col] = ap0[r] + ap2[r] + ap4[r];
            pre[ps][wv][5][quad * 4 + r][col] = ap1[r] + ap3[r] + ap5[r];
        }
        __syncthreads();   // pre[] complete

        float hn, cn;
        {
            float pi = 0.f, pf = 0.f, pg = 0.f, po = 0.f;
#pragma unroll
            for (int q = 0; q < 4; ++q) {
                pi += pre[ps][q][0][b_][j_] + pre[ps][q][4][b_][j_];
                pf += pre[ps][q][1][b_][j_] + pre[ps][q][5][b_][j_];
                pg += pre[ps][q][2][b_][j_];
                po += pre[ps][q][3][b_][j_];
            }
            const float cprev = c_loc[b_][j_];
            const float iv = sigf(pi), fv = sigf(pf), gv = tanh_(pg);
            cn = fv * cprev + iv * gv;
            float ov = sigf(po + cn);
            hn = ov * tanh_(cn);
            if (t >= my_len) { hn = 0.f; cn = 0.f; }
            c_loc[b_][j_] = cn;
            const int sidx = sl_w * 65536 + (b0 + b_) * 1024 + jbase + j_;
            unsigned short hbw  = f2b(hn);
            unsigned short chw  = f2b(cn);
            unsigned short clw  = f2b(cn - b2f(chw));
            __hip_atomic_store(&hst[sidx],   hbw, __ATOMIC_RELAXED, __HIP_MEMORY_SCOPE_AGENT);
            __hip_atomic_store(&cst[sidx],   chw, __ATOMIC_RELAXED, __HIP_MEMORY_SCOPE_AGENT);
            __hip_atomic_store(&cstlo[sidx], clw, __ATOMIC_RELAXED, __HIP_MEMORY_SCOPE_AGENT);
        }
        // Per-wave release: drain OWN state stores (this wave = rows
        // wv*4..wv*4+3, all 16 cols), post OWN flag. No block barrier.
        asm volatile("s_waitcnt vmcnt(0)" ::: "memory");
        if (lane == 0)
            __hip_atomic_store(&flags[cu * 4 + wv], t + 1,
                               __ATOMIC_RELAXED, __HIP_MEMORY_SCOPE_AGENT);
        // Out stores AFTER the flag post: off the critical path.
        const long ob = (long)(b0 + b_) * 192512 + (long)t * 1024 + jbase + j_;
        out_h[ob] = hn;
        out_c[ob] = cn;
    }
    asm volatile("" :: "v"(bl0), "v"(bl1), "v"(bl2), "v"(bl3));   // keep ballast live
}

// ---------------------------------------------------------------------------
extern "C" void kernel_launch(void* const* d_in, const int* in_sizes, int n_in,
                              void* d_out, int out_size, void* d_ws, size_t ws_size,
                              hipStream_t stream) {
    const float* x    = (const float*)d_in[0];
    const float* h0   = (const float*)d_in[1];
    const float* c0   = (const float*)d_in[2];
    const float* wih  = (const float*)d_in[3];
    const float* whh  = (const float*)d_in[4];
    const float* wrec = (const float*)d_in[5];
    const float* bias = (const float*)d_in[6];
    const int* lengths = (const int*)d_in[7];

    char* ws = (char*)d_ws;
    unsigned short* px     = (unsigned short*)(ws + WS_PX);
    unsigned short* xb     = (unsigned short*)(ws + WS_XB);
    unsigned short* wihb   = (unsigned short*)(ws + WS_WIHB);
    unsigned short* wcomb  = (unsigned short*)(ws + WS_WCOMB);
    unsigned short* hst    = (unsigned short*)(ws + WS_HST);
    unsigned short* cst    = (unsigned short*)(ws + WS_CST);
    unsigned short* wreclo = (unsigned short*)(ws + WS_WRECLO);
    unsigned short* cstlo  = (unsigned short*)(ws + WS_CSTLO);
    int* flags             = (int*)(ws + WS_FLAGS);
    float* out = (float*)d_out;

    hipLaunchKernelGGL(k_prep, dim3(2048), dim3(256), 0, stream,
                       x, h0, c0, wih, whh, wrec, xb, wihb, wcomb, hst, cst, wreclo, cstlo, flags);
    hipLaunchKernelGGL(k_px, dim3(64, 188), dim3(256), 0, stream, xb, wihb, bias, px);
    hipLaunchKernelGGL(k_scan, dim3(256), dim3(256), 0, stream,
                       wcomb, wreclo, c0, lengths, px, hst, cst, cstlo, flags, out);
}